// Round 9
// baseline (3864.121 us; speedup 1.0000x reference)
//
#include <hip/hip_runtime.h>
#include <cmath>

#define NBLK 256
#define NTH  512
#define BATCH 512
#define TENC  256
#define INSZ  32
#define HID   256
#define PREDW 30
#define NTICKS 288

typedef __attribute__((ext_vector_type(4))) float f32x4;
typedef __attribute__((ext_vector_type(8))) short short8;
typedef __attribute__((ext_vector_type(8))) __bf16 bf16x8;
typedef __attribute__((ext_vector_type(4))) unsigned int u32x4;

struct SParams {
  const float *input, *target;
  const float *eWih0, *eWhh0, *eBih0, *eBhh0;
  const float *eWih1, *eWhh1, *eBih1, *eBhh1;
  const float *dWih0, *dWhh0, *dBih0, *dBhh0;
  const float *dWih1, *dWhh1, *dBih1, *dBhh1;
  const float *fcw, *fcb;
  float *out;
  char *h0img, *h1img;   // each 1 MiB: [par2][rtile8][hl2][kt8][nt4][1024B]
  unsigned *cnt;         // 8 per-rtile counters, 256B apart
};

// Fast device transcendentals: v_exp_f32 + v_rcp_f32 (~1ulp each; error budget
// absmax<=2e-4 vs 6e-4 threshold). sig = 1/(1+e^-x); tanh = 1 - 2/(e^2x + 1).
__device__ __forceinline__ float sigf(float x) {
  return __builtin_amdgcn_rcpf(1.0f + __expf(-x));
}
__device__ __forceinline__ float tanf_fast(float x) {
  return 1.0f - 2.0f * __builtin_amdgcn_rcpf(__expf(2.0f * x) + 1.0f);
}

__device__ __forceinline__ unsigned short f2bf(float x) {
  unsigned u = __float_as_uint(x);
  u += 0x7fffu + ((u >> 16) & 1u);
  return (unsigned short)(u >> 16);
}
__device__ __forceinline__ float bf2f(unsigned short h) {
  return __uint_as_float(((unsigned)h) << 16);
}

// L2-cacheable global->LDS (aux=0). Cross-XCD freshness comes from the
// per-tick release(wbl2)/acquire(inv) pair in grid_sync.
__device__ __forceinline__ void gload_lds16(const void* g, void* l) {
  __builtin_amdgcn_global_load_lds(
      (const __attribute__((address_space(1))) unsigned int*)g,
      (__attribute__((address_space(3))) unsigned int*)l, 16, 0, 0);
}

// sc1 write-through store — kept ONLY for out-init and the parity-carry
// (LLC-atomic interop / one-off), NOT for per-tick h stores.
__device__ __forceinline__ void gstore16_sc(void* gptr, u32x4 v) {
  asm volatile("global_store_dwordx4 %0, %1, off sc0 sc1" :: "v"(gptr), "v"(v) : "memory");
}
__device__ __forceinline__ void gstore4_sc(float* gptr, float v) {
  asm volatile("global_store_dword %0, %1, off sc0 sc1" :: "v"(gptr), "v"(v) : "memory");
}

__device__ __forceinline__ f32x4 mfma16(bf16x8 a, bf16x8 b, f32x4 c) {
  return __builtin_amdgcn_mfma_f32_16x16x32_bf16(a, b, c, 0, 0, 0);
}

__device__ __forceinline__ size_t imgoff(int par, int rt, int hl, int kt, int nt) {
  return (size_t)((((par * 8 + rt) * 2 + hl) * 8 + kt) * 4 + nt) * 1024;
}

__device__ __forceinline__ void wait_vmcnt_k(int k) {
  switch (k) {
    case 0: asm volatile("s_waitcnt vmcnt(0)" ::: "memory"); break;
    case 1: asm volatile("s_waitcnt vmcnt(1)" ::: "memory"); break;
    case 2: asm volatile("s_waitcnt vmcnt(2)" ::: "memory"); break;
    case 3: asm volatile("s_waitcnt vmcnt(3)" ::: "memory"); break;
    case 4: asm volatile("s_waitcnt vmcnt(4)" ::: "memory"); break;
    default: asm volatile("s_waitcnt vmcnt(5)" ::: "memory"); break;
  }
}

// Per-rtile barrier (32 blocks): release-add (ONE buffer_wbl2: pushes this
// XCD's dirty h lines to the memory-side LLC, which allocates writebacks) +
// relaxed spin + ONE acquire load (ONE buffer_inv/tick — R6-proven cheap;
// R3's pathology was inv-per-poll). h then flows HBM-free: L2 -> LLC -> L2.
__device__ __forceinline__ void grid_sync(unsigned* cnt, unsigned tgt) {
  asm volatile("s_waitcnt vmcnt(0)" ::: "memory");  // own stores in L2
  __syncthreads();
  if (threadIdx.x == 0) {
    __hip_atomic_fetch_add(cnt, 1u, __ATOMIC_RELEASE, __HIP_MEMORY_SCOPE_AGENT);
    while (__hip_atomic_load(cnt, __ATOMIC_RELAXED, __HIP_MEMORY_SCOPE_AGENT) < tgt) { }
    (void)__hip_atomic_load(cnt, __ATOMIC_ACQUIRE, __HIP_MEMORY_SCOPE_AGENT);
  }
  __syncthreads();
  asm volatile("" ::: "memory");
}

extern __shared__ char smem[];

__global__ __launch_bounds__(NTH, 2) void seq2seq_kernel(SParams p)
{
  const int tid  = threadIdx.x;
  const int bid  = blockIdx.x;
  const int lane = tid & 63;
  const int wid  = tid >> 6;

  // rtile = bid&7: one rtile's pipeline clusters on one XCD under round-robin
  // dispatch -> with write-back h, consumer re-reads hit the shared L2.
  const int rtile = bid & 7;
  const int role  = bid >> 3;          // 0..31
  const int layer = role >> 4;         // 0,1
  const int dtile = role & 15;
  const int R0 = rtile * 64;
  const int D0 = dtile * 16;

  const int m    = wid >> 1;           // mtile 0..3
  const int jj   = wid & 1;            // ntile pair {2jj, 2jj+1}
  const int bl15 = lane & 15;
  const int k8l  = lane >> 4;          // 0..3
  const int dim_local = m * 4 + (lane >> 4);
  const int dim  = D0 + dim_local;

  // LDS: ring 8 x 8KB (h staging) + xbuf 8KB (L0 enc). Weights live in VGPRs.
  char* ring = smem;
  char* xbuf = smem + 8 * 8192;
  unsigned* h_img = (unsigned*)smem;   // alias ring slot0 (post-loop use only)

  unsigned* mycnt = p.cnt + rtile * 64;

  // ---- biases / fc / dec-x weights into regs ----
  const float *bi_e, *bh_e, *bi_d, *bh_d;
  if (layer == 0) { bi_e = p.eBih0; bh_e = p.eBhh0; bi_d = p.dBih0; bh_d = p.dBhh0; }
  else            { bi_e = p.eBih1; bh_e = p.eBhh1; bi_d = p.dBih1; bh_d = p.dBhh1; }
  float be[4], bd[4], wxd[4];
  #pragma unroll
  for (int g = 0; g < 4; ++g) {
    const int grow = g * HID + dim;
    be[g]  = bi_e[grow] + bh_e[grow];
    bd[g]  = bi_d[grow] + bh_d[grow];
    wxd[g] = (layer == 0) ? p.dWih0[grow] : 0.0f;
  }
  const float fcwj = p.fcw[dim];
  const float fcb0 = p.fcb[0];

  // init output to fc bias (sc1: LLC atomicAdds later must not race dirty L2)
  for (int idx = bid * NTH + tid; idx < BATCH * PREDW; idx += NBLK * NTH)
    gstore4_sc(p.out + idx, fcb0);

  // ---- weights fp32 -> split-bf16 A-frags, directly into REGISTERS ----
  const int wrow = (bl15 & 3) * HID + D0 + m * 4 + (bl15 >> 2);
  auto convReg = [&](const float* __restrict__ W, int K, int kt, bf16x8& hf, bf16x8& lf) {
    const float* src = W + (size_t)wrow * K + (size_t)(kt * 4 + k8l) * 8;
    float4 v0 = *(const float4*)src;
    float4 v1 = *(const float4*)(src + 4);
    float v[8] = {v0.x, v0.y, v0.z, v0.w, v1.x, v1.y, v1.z, v1.w};
    short8 hs, ls;
    #pragma unroll
    for (int e = 0; e < 8; ++e) {
      unsigned short hq = f2bf(v[e]);
      hs[e] = (short)hq;
      ls[e] = (short)f2bf(v[e] - bf2f(hq));
    }
    hf = __builtin_bit_cast(bf16x8, hs);
    lf = __builtin_bit_cast(bf16x8, ls);
  };

  bf16x8 wh[16], wl[16];   // statically indexed only (rule #20)
  if (layer == 0) {
    convReg(p.eWih0, INSZ, 0, wh[0], wl[0]);
    #pragma unroll
    for (int kt = 0; kt < 8; ++kt) convReg(p.eWhh0, HID, kt, wh[1 + kt], wl[1 + kt]);
  } else {
    #pragma unroll
    for (int kt = 0; kt < 8; ++kt) convReg(p.eWih1, HID, kt, wh[kt], wl[kt]);
    #pragma unroll
    for (int kt = 0; kt < 8; ++kt) convReg(p.eWhh1, HID, kt, wh[8 + kt], wl[8 + kt]);
  }

  float c0 = 0.0f, c1 = 0.0f;
  unsigned epoch = 1;

  for (int t = 0; t < NTICKS; ++t) {
    const int rp = t & 1, wp = rp ^ 1;

    bool active = false, isdec = false;
    int s = 0;
    if (layer == 0) {
      if (t < 256)                 { active = true; }
      else if (t >= 257 && t < 287){ active = true; isdec = true; s = t - 257; }
    } else {
      if (t >= 1 && t <= 256)      { active = true; }
      else if (t >= 258)           { active = true; isdec = true; s = t - 258; }
    }

    if (active) {
      f32x4 a0, a1;
      #pragma unroll
      for (int q = 0; q < 4; ++q) {
        const float b = isdec ? bd[q] : be[q];
        a0[q] = b; a1[q] = b;
      }

      auto ringIssue = [&](int st, int slot) {
        const int hl = wid >> 2, nt = wid & 3;
        const char* base; int kt;
        if (layer == 0) { base = p.h0img; kt = st; }
        else { base = (st >= 8) ? p.h1img : p.h0img; kt = st & 7; }
        const char* g = base + imgoff(rp, rtile, hl, kt, nt) + (size_t)lane * 16;
        gload_lds16(g, ring + (size_t)slot * 8192 + (hl * 4 + nt) * 1024);
      };

      // L0 enc: stage x[t] FIRST (its compiler-inserted vmcnt(0) must not
      // drain the ring prefetches issued below)
      if (layer == 0 && !isdec) {
        if (tid < 256) {
          const int b = tid >> 2, k8 = tid & 3;
          const float* src = p.input + (size_t)(R0 + b) * TENC * INSZ + t * INSZ + k8 * 8;
          float4 v0 = *(const float4*)src;
          float4 v1 = *(const float4*)(src + 4);
          float v[8] = {v0.x, v0.y, v0.z, v0.w, v1.x, v1.y, v1.z, v1.w};
          short8 h8, l8;
          #pragma unroll
          for (int q = 0; q < 8; ++q) {
            unsigned short hq = f2bf(v[q]);
            h8[q] = (short)hq;
            l8[q] = (short)f2bf(v[q] - bf2f(hq));
          }
          const int li = (b & 15) | (k8 << 4), nt = b >> 4;
          *(short8*)(xbuf + (size_t)(0 * 4 + nt) * 1024 + li * 16) = h8;
          *(short8*)(xbuf + (size_t)(1 * 4 + nt) * 1024 + li * 16) = l8;
        }
      }

      // 6-deep ring prologue
      #pragma unroll
      for (int st = 0; st < 6; ++st) ringIssue(st, st);

      // L0 enc GEMM-A (Wih0 x xbuf) overlaps the prefetch flight
      if (layer == 0 && !isdec) {
        __syncthreads();
        bf16x8 b0h = *(const bf16x8*)(xbuf + (size_t)(0 + 2 * jj + 0) * 1024 + lane * 16);
        bf16x8 b0l = *(const bf16x8*)(xbuf + (size_t)(4 + 2 * jj + 0) * 1024 + lane * 16);
        bf16x8 b1h = *(const bf16x8*)(xbuf + (size_t)(0 + 2 * jj + 1) * 1024 + lane * 16);
        bf16x8 b1l = *(const bf16x8*)(xbuf + (size_t)(4 + 2 * jj + 1) * 1024 + lane * 16);
        a0 = mfma16(wh[0], b0h, a0); a0 = mfma16(wh[0], b0l, a0); a0 = mfma16(wl[0], b0h, a0);
        a1 = mfma16(wh[0], b1h, a1); a1 = mfma16(wh[0], b1l, a1); a1 = mfma16(wl[0], b1h, a1);
      }

      // main ring loop: counted vmcnt -> barrier -> issue(i+6) -> 6 MFMA.
      auto ringStep = [&](int i, int NS, bf16x8 ah, bf16x8 al) {
        const int kk = NS - 1 - i;
        wait_vmcnt_k(kk < 5 ? kk : 5);
        __builtin_amdgcn_s_barrier();
        asm volatile("" ::: "memory");
        if (i + 6 < NS) ringIssue(i + 6, (i + 6) & 7);
        char* sp = ring + (size_t)(i & 7) * 8192;
        bf16x8 b0h = *(const bf16x8*)(sp + (size_t)(0 + 2 * jj + 0) * 1024 + lane * 16);
        bf16x8 b0l = *(const bf16x8*)(sp + (size_t)(4 + 2 * jj + 0) * 1024 + lane * 16);
        bf16x8 b1h = *(const bf16x8*)(sp + (size_t)(0 + 2 * jj + 1) * 1024 + lane * 16);
        bf16x8 b1l = *(const bf16x8*)(sp + (size_t)(4 + 2 * jj + 1) * 1024 + lane * 16);
        a0 = mfma16(ah, b0h, a0); a0 = mfma16(ah, b0l, a0); a0 = mfma16(al, b0h, a0);
        a1 = mfma16(ah, b1h, a1); a1 = mfma16(ah, b1l, a1); a1 = mfma16(al, b1h, a1);
      };
      if (layer == 0) {
        #pragma unroll
        for (int i = 0; i < 8; ++i) ringStep(i, 8, wh[1 + i], wl[1 + i]);
      } else {
        #pragma unroll
        for (int i = 0; i < 16; ++i) ringStep(i, 16, wh[i], wl[i]);
      }
      __syncthreads();   // ring drained; h_img alias region now free

      // ---- epilogue: gates in-lane; c in regs; h -> h_img ----
      #pragma unroll
      for (int nt = 0; nt < 2; ++nt) {
        f32x4 a = nt ? a1 : a0;
        const int bg = R0 + (2 * jj + nt) * 16 + bl15;
        if (isdec && layer == 0) {
          const float xv = p.target[bg * PREDW + s];
          #pragma unroll
          for (int q = 0; q < 4; ++q) a[q] = fmaf(xv, wxd[q], a[q]);
        }
        const float ig = sigf(a[0]);
        const float fg = sigf(a[1]);
        const float gg = tanf_fast(a[2]);
        const float og = sigf(a[3]);
        float& cr = nt ? c1 : c0;
        cr = fg * cr + ig * gg;
        const float h = og * tanf_fast(cr);
        if (isdec && layer == 1) {
          float pp = fcwj * h;
          pp += __shfl_xor(pp, 16);
          pp += __shfl_xor(pp, 32);
          if (lane < 16) atomicAdd(p.out + bg * PREDW + s, pp);
        }
        const unsigned hi = f2bf(h);
        const unsigned lo = f2bf(h - bf2f((unsigned short)hi));
        h_img[dim_local * 65 + (2 * jj + nt) * 16 + bl15] = (hi << 16) | lo;
      }
      __syncthreads();

      // assemble 16B chunks; PLAIN write-back store to the parity-wp image
      // (released to LLC by grid_sync's RELEASE wbl2)
      if (tid < 256) {
        const int hl = tid >> 7, t2 = tid & 127;
        const int nt = t2 >> 5, lg = (t2 >> 4) & 1, bl = t2 & 15;
        unsigned w[4];
        #pragma unroll
        for (int q = 0; q < 4; ++q) {
          const unsigned v0 = h_img[(lg * 8 + 2 * q) * 65 + nt * 16 + bl];
          const unsigned v1 = h_img[(lg * 8 + 2 * q + 1) * 65 + nt * 16 + bl];
          w[q] = hl ? (((v1 & 0xffffu) << 16) | (v0 & 0xffffu))
                    : ((v1 & 0xffff0000u) | (v0 >> 16));
        }
        const int kg = ((dtile & 1) * 2) + lg, kt = dtile >> 1;
        char* base = layer ? p.h1img : p.h0img;
        u32x4 val; val.x = w[0]; val.y = w[1]; val.z = w[2]; val.w = w[3];
        *(u32x4*)(base + imgoff(wp, rtile, hl, kt, nt) + (size_t)(bl | (kg << 4)) * 16) = val;
      }
    } else if ((layer == 0 && t == 256) || (layer == 1 && t == 257)) {
      // parity-carry own h slice rp->wp, then swap decoder weights into regs
      if (tid < 256) {
        const int hl = tid >> 7, t2 = tid & 127;
        const int nt = t2 >> 5, lg = (t2 >> 4) & 1, bl = t2 & 15;
        const int kg = ((dtile & 1) * 2) + lg, kt = dtile >> 1;
        char* base = layer ? p.h1img : p.h0img;
        const size_t sl = (size_t)(bl | (kg << 4)) * 16;
        u32x4 v = *(const u32x4*)(base + imgoff(rp, rtile, hl, kt, nt) + sl);
        *(u32x4*)(base + imgoff(wp, rtile, hl, kt, nt) + sl) = v;
      }
      if (layer == 0) {
        #pragma unroll
        for (int kt = 0; kt < 8; ++kt) convReg(p.dWhh0, HID, kt, wh[1 + kt], wl[1 + kt]);
      } else {
        #pragma unroll
        for (int kt = 0; kt < 8; ++kt) convReg(p.dWih1, HID, kt, wh[kt], wl[kt]);
        #pragma unroll
        for (int kt = 0; kt < 8; ++kt) convReg(p.dWhh1, HID, kt, wh[8 + kt], wl[8 + kt]);
      }
    }

    grid_sync(mycnt, 32u * epoch);
    ++epoch;
  }
}

extern "C" void kernel_launch(void* const* d_in, const int* in_sizes, int n_in,
                              void* d_out, int out_size, void* d_ws, size_t ws_size,
                              hipStream_t stream)
{
  SParams p;
  p.input = (const float*)d_in[0];
  p.target = (const float*)d_in[1];
  p.eWih0 = (const float*)d_in[2];  p.eWhh0 = (const float*)d_in[3];
  p.eBih0 = (const float*)d_in[4];  p.eBhh0 = (const float*)d_in[5];
  p.eWih1 = (const float*)d_in[6];  p.eWhh1 = (const float*)d_in[7];
  p.eBih1 = (const float*)d_in[8];  p.eBhh1 = (const float*)d_in[9];
  p.dWih0 = (const float*)d_in[10]; p.dWhh0 = (const float*)d_in[11];
  p.dBih0 = (const float*)d_in[12]; p.dBhh0 = (const float*)d_in[13];
  p.dWih1 = (const float*)d_in[14]; p.dWhh1 = (const float*)d_in[15];
  p.dBih1 = (const float*)d_in[16]; p.dBhh1 = (const float*)d_in[17];
  p.fcw = (const float*)d_in[18];   p.fcb = (const float*)d_in[19];
  p.out = (float*)d_out;

  char* ws = (char*)d_ws;
  p.h0img = ws;                        // 1 MiB
  p.h1img = ws + (1 << 20);            // 1 MiB
  p.cnt   = (unsigned*)(ws + (2 << 20));  // 8 counters, 256B apart

  (void)hipMemsetAsync(d_ws, 0, (size_t)(2 << 20) + 2048, stream);

  const int shmem = 8 * 8192 + 8192;   // 72 KiB: ring + xbuf
  (void)hipFuncSetAttribute((const void*)seq2seq_kernel,
                            hipFuncAttributeMaxDynamicSharedMemorySize, shmem);
  hipLaunchKernelGGL(seq2seq_kernel, dim3(NBLK), dim3(NTH), shmem, stream, p);
}

// Round 10
// 2764.396 us; speedup vs baseline: 1.3978x; 1.3978x over previous
//
#include <hip/hip_runtime.h>
#include <cmath>

#define NBLK 256
#define NTH  512
#define BATCH 512
#define TENC  256
#define INSZ  32
#define HID   256
#define PREDW 30
#define NTICKS 288

typedef __attribute__((ext_vector_type(4))) float f32x4;
typedef __attribute__((ext_vector_type(8))) short short8;
typedef __attribute__((ext_vector_type(8))) __bf16 bf16x8;
typedef __attribute__((ext_vector_type(4))) unsigned int u32x4;

struct SParams {
  const float *input, *target;
  const float *eWih0, *eWhh0, *eBih0, *eBhh0;
  const float *eWih1, *eWhh1, *eBih1, *eBhh1;
  const float *dWih0, *dWhh0, *dBih0, *dBhh0;
  const float *dWih1, *dWhh1, *dBih1, *dBhh1;
  const float *fcw, *fcb;
  float *out;
  char *h0img, *h1img;   // each 1 MiB: [par2][rtile8][hl2][kt8][nt4][1024B]
  unsigned *cnt;         // 8 per-rtile counters (256B apart), then gcnt/badflag/xccslot
};

// Fast transcendentals (R9-proven: absmax unchanged 6.1e-5)
__device__ __forceinline__ float sigf(float x) {
  return __builtin_amdgcn_rcpf(1.0f + __expf(-x));
}
__device__ __forceinline__ float tanf_fast(float x) {
  return 1.0f - 2.0f * __builtin_amdgcn_rcpf(__expf(2.0f * x) + 1.0f);
}

__device__ __forceinline__ unsigned short f2bf(float x) {
  unsigned u = __float_as_uint(x);
  u += 0x7fffu + ((u >> 16) & 1u);
  return (unsigned short)(u >> 16);
}
__device__ __forceinline__ float bf2f(unsigned short h) {
  return __uint_as_float(((unsigned)h) << 16);
}

// global->LDS ring load. fast: sc0 (bypass L1, hit same-XCD L2 — fresh via
// producers' write-through). fallback: sc0|sc1 (LLC-direct, R5/R8-proven).
__device__ __forceinline__ void gload_lds16_p(const void* g, void* l, bool fast) {
  if (fast)
    __builtin_amdgcn_global_load_lds(
        (const __attribute__((address_space(1))) unsigned int*)g,
        (__attribute__((address_space(3))) unsigned int*)l, 16, 0, 1);
  else
    __builtin_amdgcn_global_load_lds(
        (const __attribute__((address_space(1))) unsigned int*)g,
        (__attribute__((address_space(3))) unsigned int*)l, 16, 0, 17);
}

// Write-through store: updates hitting L2 line (same-XCD visibility) AND
// reaches the LLC (cross-XCD fallback visibility).
__device__ __forceinline__ void gstore16_sc(void* gptr, u32x4 v) {
  asm volatile("global_store_dwordx4 %0, %1, off sc0 sc1" :: "v"(gptr), "v"(v) : "memory");
}
__device__ __forceinline__ void gstore4_sc(float* gptr, float v) {
  asm volatile("global_store_dword %0, %1, off sc0 sc1" :: "v"(gptr), "v"(v) : "memory");
}
__device__ __forceinline__ u32x4 gload16_coh(const void* gptr, bool fast) {
  u32x4 r;
  if (fast)
    asm volatile("global_load_dwordx4 %0, %1, off sc0" : "=v"(r) : "v"(gptr) : "memory");
  else
    asm volatile("global_load_dwordx4 %0, %1, off sc0 sc1" : "=v"(r) : "v"(gptr) : "memory");
  asm volatile("s_waitcnt vmcnt(0)" ::: "memory");
  return r;
}

__device__ __forceinline__ unsigned get_xcc() {
  unsigned x;
  asm volatile("s_getreg_b32 %0, hwreg(HW_REG_XCC_ID)" : "=s"(x));
  return x;
}

__device__ __forceinline__ f32x4 mfma16(bf16x8 a, bf16x8 b, f32x4 c) {
  return __builtin_amdgcn_mfma_f32_16x16x32_bf16(a, b, c, 0, 0, 0);
}

__device__ __forceinline__ size_t imgoff(int par, int rt, int hl, int kt, int nt) {
  return (size_t)((((par * 8 + rt) * 2 + hl) * 8 + kt) * 4 + nt) * 1024;
}

__device__ __forceinline__ void wait_vmcnt_k(int k) {
  switch (k) {
    case 0: asm volatile("s_waitcnt vmcnt(0)" ::: "memory"); break;
    case 1: asm volatile("s_waitcnt vmcnt(1)" ::: "memory"); break;
    case 2: asm volatile("s_waitcnt vmcnt(2)" ::: "memory"); break;
    case 3: asm volatile("s_waitcnt vmcnt(3)" ::: "memory"); break;
    case 4: asm volatile("s_waitcnt vmcnt(4)" ::: "memory"); break;
    default: asm volatile("s_waitcnt vmcnt(5)" ::: "memory"); break;
  }
}

// Pure-relaxed barrier (R8-proven): no cache maintenance anywhere.
__device__ __forceinline__ void barrier_on(unsigned* cnt, unsigned tgt) {
  asm volatile("s_waitcnt vmcnt(0)" ::: "memory");  // own stores at their cache point
  __syncthreads();
  if (threadIdx.x == 0) {
    __hip_atomic_fetch_add(cnt, 1u, __ATOMIC_RELAXED, __HIP_MEMORY_SCOPE_AGENT);
    while (__hip_atomic_load(cnt, __ATOMIC_RELAXED, __HIP_MEMORY_SCOPE_AGENT) < tgt) { }
  }
  __syncthreads();
  asm volatile("" ::: "memory");
}

extern __shared__ char smem[];

__global__ __launch_bounds__(NTH, 2) void seq2seq_kernel(SParams p)
{
  const int tid  = threadIdx.x;
  const int bid  = blockIdx.x;
  const int lane = tid & 63;
  const int wid  = tid >> 6;

  // rtile = bid&7: one rtile's pipeline clusters on one XCD under round-robin
  // dispatch. Exploited for L2-local h exchange — but VERIFIED at runtime
  // below; on mismatch we fall back to the LLC path (G16-compliant).
  const int rtile = bid & 7;
  const int role  = bid >> 3;          // 0..31
  const int layer = role >> 4;         // 0,1
  const int dtile = role & 15;
  const int R0 = rtile * 64;
  const int D0 = dtile * 16;

  const int m    = wid >> 1;           // mtile 0..3
  const int jj   = wid & 1;            // ntile pair {2jj, 2jj+1}
  const int bl15 = lane & 15;
  const int k8l  = lane >> 4;          // 0..3
  const int dim_local = m * 4 + (lane >> 4);
  const int dim  = D0 + dim_local;

  // LDS: ring 8 x 8KB (h staging) + xbuf 8KB (L0 enc). Weights live in VGPRs.
  char* ring = smem;
  char* xbuf = smem + 8 * 8192;
  unsigned* h_img = (unsigned*)smem;   // alias ring slot0 (post-loop use only)

  unsigned* mycnt   = p.cnt + rtile * 64;       // per-rtile barrier counters
  unsigned* gcnt    = p.cnt + 512;              // one-time full-grid counter
  unsigned* badflag = p.cnt + 513;
  unsigned* xccslot = p.cnt + 516;              // [8]

  // ---- XCD-mapping verification (one-time) ----
  const unsigned myxcc = get_xcc();
  if (tid == 0 && role == 0)
    __hip_atomic_store(&xccslot[rtile], myxcc, __ATOMIC_RELAXED, __HIP_MEMORY_SCOPE_AGENT);
  barrier_on(gcnt, NBLK);                       // slot stores drained by vmcnt(0)
  if (tid == 0) {
    unsigned lead = __hip_atomic_load(&xccslot[rtile], __ATOMIC_RELAXED, __HIP_MEMORY_SCOPE_AGENT);
    if (lead != myxcc)
      __hip_atomic_fetch_or(badflag, 1u, __ATOMIC_RELAXED, __HIP_MEMORY_SCOPE_AGENT);
  }
  barrier_on(gcnt, 2u * NBLK);
  if (tid == 0)
    ((unsigned*)smem)[0] =
        __hip_atomic_load(badflag, __ATOMIC_RELAXED, __HIP_MEMORY_SCOPE_AGENT);
  __syncthreads();
  const bool fastp = (((unsigned*)smem)[0] == 0);
  __syncthreads();

  // ---- biases / fc / dec-x weights into regs ----
  const float *bi_e, *bh_e, *bi_d, *bh_d;
  if (layer == 0) { bi_e = p.eBih0; bh_e = p.eBhh0; bi_d = p.dBih0; bh_d = p.dBhh0; }
  else            { bi_e = p.eBih1; bh_e = p.eBhh1; bi_d = p.dBih1; bh_d = p.dBhh1; }
  float be[4], bd[4], wxd[4];
  #pragma unroll
  for (int g = 0; g < 4; ++g) {
    const int grow = g * HID + dim;
    be[g]  = bi_e[grow] + bh_e[grow];
    bd[g]  = bi_d[grow] + bh_d[grow];
    wxd[g] = (layer == 0) ? p.dWih0[grow] : 0.0f;
  }
  const float fcwj = p.fcw[dim];
  const float fcb0 = p.fcb[0];

  // init output to fc bias (sc1: LLC atomicAdds later must not race dirty L2)
  for (int idx = bid * NTH + tid; idx < BATCH * PREDW; idx += NBLK * NTH)
    gstore4_sc(p.out + idx, fcb0);

  // ---- weights fp32 -> split-bf16 A-frags, directly into REGISTERS ----
  const int wrow = (bl15 & 3) * HID + D0 + m * 4 + (bl15 >> 2);
  auto convReg = [&](const float* __restrict__ W, int K, int kt, bf16x8& hf, bf16x8& lf) {
    const float* src = W + (size_t)wrow * K + (size_t)(kt * 4 + k8l) * 8;
    float4 v0 = *(const float4*)src;
    float4 v1 = *(const float4*)(src + 4);
    float v[8] = {v0.x, v0.y, v0.z, v0.w, v1.x, v1.y, v1.z, v1.w};
    short8 hs, ls;
    #pragma unroll
    for (int e = 0; e < 8; ++e) {
      unsigned short hq = f2bf(v[e]);
      hs[e] = (short)hq;
      ls[e] = (short)f2bf(v[e] - bf2f(hq));
    }
    hf = __builtin_bit_cast(bf16x8, hs);
    lf = __builtin_bit_cast(bf16x8, ls);
  };

  bf16x8 wh[16], wl[16];   // statically indexed only (rule #20)
  if (layer == 0) {
    convReg(p.eWih0, INSZ, 0, wh[0], wl[0]);
    #pragma unroll
    for (int kt = 0; kt < 8; ++kt) convReg(p.eWhh0, HID, kt, wh[1 + kt], wl[1 + kt]);
  } else {
    #pragma unroll
    for (int kt = 0; kt < 8; ++kt) convReg(p.eWih1, HID, kt, wh[kt], wl[kt]);
    #pragma unroll
    for (int kt = 0; kt < 8; ++kt) convReg(p.eWhh1, HID, kt, wh[8 + kt], wl[8 + kt]);
  }

  float c0 = 0.0f, c1 = 0.0f;
  unsigned epoch = 1;

  for (int t = 0; t < NTICKS; ++t) {
    const int rp = t & 1, wp = rp ^ 1;

    bool active = false, isdec = false;
    int s = 0;
    if (layer == 0) {
      if (t < 256)                 { active = true; }
      else if (t >= 257 && t < 287){ active = true; isdec = true; s = t - 257; }
    } else {
      if (t >= 1 && t <= 256)      { active = true; }
      else if (t >= 258)           { active = true; isdec = true; s = t - 258; }
    }

    if (active) {
      f32x4 a0, a1;
      #pragma unroll
      for (int q = 0; q < 4; ++q) {
        const float b = isdec ? bd[q] : be[q];
        a0[q] = b; a1[q] = b;
      }

      auto ringIssue = [&](int st, int slot) {
        const int hl = wid >> 2, nt = wid & 3;
        const char* base; int kt;
        if (layer == 0) { base = p.h0img; kt = st; }
        else { base = (st >= 8) ? p.h1img : p.h0img; kt = st & 7; }
        const char* g = base + imgoff(rp, rtile, hl, kt, nt) + (size_t)lane * 16;
        gload_lds16_p(g, ring + (size_t)slot * 8192 + (hl * 4 + nt) * 1024, fastp);
      };

      // L0 enc: stage x[t] FIRST (its compiler-inserted vmcnt(0) must not
      // drain the ring prefetches issued below)
      if (layer == 0 && !isdec) {
        if (tid < 256) {
          const int b = tid >> 2, k8 = tid & 3;
          const float* src = p.input + (size_t)(R0 + b) * TENC * INSZ + t * INSZ + k8 * 8;
          float4 v0 = *(const float4*)src;
          float4 v1 = *(const float4*)(src + 4);
          float v[8] = {v0.x, v0.y, v0.z, v0.w, v1.x, v1.y, v1.z, v1.w};
          short8 h8, l8;
          #pragma unroll
          for (int q = 0; q < 8; ++q) {
            unsigned short hq = f2bf(v[q]);
            h8[q] = (short)hq;
            l8[q] = (short)f2bf(v[q] - bf2f(hq));
          }
          const int li = (b & 15) | (k8 << 4), nt = b >> 4;
          *(short8*)(xbuf + (size_t)(0 * 4 + nt) * 1024 + li * 16) = h8;
          *(short8*)(xbuf + (size_t)(1 * 4 + nt) * 1024 + li * 16) = l8;
        }
      }

      // 6-deep ring prologue
      #pragma unroll
      for (int st = 0; st < 6; ++st) ringIssue(st, st);

      // L0 enc GEMM-A (Wih0 x xbuf) overlaps the prefetch flight
      if (layer == 0 && !isdec) {
        __syncthreads();
        bf16x8 b0h = *(const bf16x8*)(xbuf + (size_t)(0 + 2 * jj + 0) * 1024 + lane * 16);
        bf16x8 b0l = *(const bf16x8*)(xbuf + (size_t)(4 + 2 * jj + 0) * 1024 + lane * 16);
        bf16x8 b1h = *(const bf16x8*)(xbuf + (size_t)(0 + 2 * jj + 1) * 1024 + lane * 16);
        bf16x8 b1l = *(const bf16x8*)(xbuf + (size_t)(4 + 2 * jj + 1) * 1024 + lane * 16);
        a0 = mfma16(wh[0], b0h, a0); a0 = mfma16(wh[0], b0l, a0); a0 = mfma16(wl[0], b0h, a0);
        a1 = mfma16(wh[0], b1h, a1); a1 = mfma16(wh[0], b1l, a1); a1 = mfma16(wl[0], b1h, a1);
      }

      // main ring loop: counted vmcnt -> barrier -> issue(i+6) -> 6 MFMA.
      auto ringStep = [&](int i, int NS, bf16x8 ah, bf16x8 al) {
        const int kk = NS - 1 - i;
        wait_vmcnt_k(kk < 5 ? kk : 5);
        __builtin_amdgcn_s_barrier();
        asm volatile("" ::: "memory");
        if (i + 6 < NS) ringIssue(i + 6, (i + 6) & 7);
        char* sp = ring + (size_t)(i & 7) * 8192;
        bf16x8 b0h = *(const bf16x8*)(sp + (size_t)(0 + 2 * jj + 0) * 1024 + lane * 16);
        bf16x8 b0l = *(const bf16x8*)(sp + (size_t)(4 + 2 * jj + 0) * 1024 + lane * 16);
        bf16x8 b1h = *(const bf16x8*)(sp + (size_t)(0 + 2 * jj + 1) * 1024 + lane * 16);
        bf16x8 b1l = *(const bf16x8*)(sp + (size_t)(4 + 2 * jj + 1) * 1024 + lane * 16);
        a0 = mfma16(ah, b0h, a0); a0 = mfma16(ah, b0l, a0); a0 = mfma16(al, b0h, a0);
        a1 = mfma16(ah, b1h, a1); a1 = mfma16(ah, b1l, a1); a1 = mfma16(al, b1h, a1);
      };
      if (layer == 0) {
        #pragma unroll
        for (int i = 0; i < 8; ++i) ringStep(i, 8, wh[1 + i], wl[1 + i]);
      } else {
        #pragma unroll
        for (int i = 0; i < 16; ++i) ringStep(i, 16, wh[i], wl[i]);
      }
      __syncthreads();   // ring drained; h_img alias region now free

      // ---- epilogue: gates in-lane; c in regs; h -> h_img ----
      #pragma unroll
      for (int nt = 0; nt < 2; ++nt) {
        f32x4 a = nt ? a1 : a0;
        const int bg = R0 + (2 * jj + nt) * 16 + bl15;
        if (isdec && layer == 0) {
          const float xv = p.target[bg * PREDW + s];
          #pragma unroll
          for (int q = 0; q < 4; ++q) a[q] = fmaf(xv, wxd[q], a[q]);
        }
        const float ig = sigf(a[0]);
        const float fg = sigf(a[1]);
        const float gg = tanf_fast(a[2]);
        const float og = sigf(a[3]);
        float& cr = nt ? c1 : c0;
        cr = fg * cr + ig * gg;
        const float h = og * tanf_fast(cr);
        if (isdec && layer == 1) {
          float pp = fcwj * h;
          pp += __shfl_xor(pp, 16);
          pp += __shfl_xor(pp, 32);
          if (lane < 16) atomicAdd(p.out + bg * PREDW + s, pp);
        }
        const unsigned hi = f2bf(h);
        const unsigned lo = f2bf(h - bf2f((unsigned short)hi));
        h_img[dim_local * 65 + (2 * jj + nt) * 16 + bl15] = (hi << 16) | lo;
      }
      __syncthreads();

      // assemble 16B chunks; write-through store to the parity-wp image
      if (tid < 256) {
        const int hl = tid >> 7, t2 = tid & 127;
        const int nt = t2 >> 5, lg = (t2 >> 4) & 1, bl = t2 & 15;
        unsigned w[4];
        #pragma unroll
        for (int q = 0; q < 4; ++q) {
          const unsigned v0 = h_img[(lg * 8 + 2 * q) * 65 + nt * 16 + bl];
          const unsigned v1 = h_img[(lg * 8 + 2 * q + 1) * 65 + nt * 16 + bl];
          w[q] = hl ? (((v1 & 0xffffu) << 16) | (v0 & 0xffffu))
                    : ((v1 & 0xffff0000u) | (v0 >> 16));
        }
        const int kg = ((dtile & 1) * 2) + lg, kt = dtile >> 1;
        char* base = layer ? p.h1img : p.h0img;
        u32x4 val; val.x = w[0]; val.y = w[1]; val.z = w[2]; val.w = w[3];
        gstore16_sc(base + imgoff(wp, rtile, hl, kt, nt) + (size_t)(bl | (kg << 4)) * 16, val);
      }
    } else if ((layer == 0 && t == 256) || (layer == 1 && t == 257)) {
      // parity-carry own h slice rp->wp, then swap decoder weights into regs
      if (tid < 256) {
        const int hl = tid >> 7, t2 = tid & 127;
        const int nt = t2 >> 5, lg = (t2 >> 4) & 1, bl = t2 & 15;
        const int kg = ((dtile & 1) * 2) + lg, kt = dtile >> 1;
        char* base = layer ? p.h1img : p.h0img;
        const size_t sl = (size_t)(bl | (kg << 4)) * 16;
        u32x4 v = gload16_coh(base + imgoff(rp, rtile, hl, kt, nt) + sl, fastp);
        gstore16_sc(base + imgoff(wp, rtile, hl, kt, nt) + sl, v);
      }
      if (layer == 0) {
        #pragma unroll
        for (int kt = 0; kt < 8; ++kt) convReg(p.dWhh0, HID, kt, wh[1 + kt], wl[1 + kt]);
      } else {
        #pragma unroll
        for (int kt = 0; kt < 8; ++kt) convReg(p.dWih1, HID, kt, wh[kt], wl[kt]);
        #pragma unroll
        for (int kt = 0; kt < 8; ++kt) convReg(p.dWhh1, HID, kt, wh[8 + kt], wl[8 + kt]);
      }
    }

    barrier_on(mycnt, 32u * epoch);
    ++epoch;
  }
}

extern "C" void kernel_launch(void* const* d_in, const int* in_sizes, int n_in,
                              void* d_out, int out_size, void* d_ws, size_t ws_size,
                              hipStream_t stream)
{
  SParams p;
  p.input = (const float*)d_in[0];
  p.target = (const float*)d_in[1];
  p.eWih0 = (const float*)d_in[2];  p.eWhh0 = (const float*)d_in[3];
  p.eBih0 = (const float*)d_in[4];  p.eBhh0 = (const float*)d_in[5];
  p.eWih1 = (const float*)d_in[6];  p.eWhh1 = (const float*)d_in[7];
  p.eBih1 = (const float*)d_in[8];  p.eBhh1 = (const float*)d_in[9];
  p.dWih0 = (const float*)d_in[10]; p.dWhh0 = (const float*)d_in[11];
  p.dBih0 = (const float*)d_in[12]; p.dBhh0 = (const float*)d_in[13];
  p.dWih1 = (const float*)d_in[14]; p.dWhh1 = (const float*)d_in[15];
  p.dBih1 = (const float*)d_in[16]; p.dBhh1 = (const float*)d_in[17];
  p.fcw = (const float*)d_in[18];   p.fcb = (const float*)d_in[19];
  p.out = (float*)d_out;

  char* ws = (char*)d_ws;
  p.h0img = ws;                        // 1 MiB
  p.h1img = ws + (1 << 20);            // 1 MiB
  p.cnt   = (unsigned*)(ws + (2 << 20));  // rtile counters + gcnt/badflag/xccslot

  (void)hipMemsetAsync(d_ws, 0, (size_t)(2 << 20) + 4096, stream);

  const int shmem = 8 * 8192 + 8192;   // 72 KiB: ring + xbuf
  (void)hipFuncSetAttribute((const void*)seq2seq_kernel,
                            hipFuncAttributeMaxDynamicSharedMemorySize, shmem);
  hipLaunchKernelGGL(seq2seq_kernel, dim3(NBLK), dim3(NTH), shmem, stream, p);
}